// Round 7
// baseline (6112.583 us; speedup 1.0000x reference)
//
#include <hip/hip_runtime.h>
#include <stdint.h>

#define BB 64
#define TT 2048
#define KK 128

typedef float f32x16 __attribute__((ext_vector_type(16)));
typedef float f32x2  __attribute__((ext_vector_type(2)));

__device__ __forceinline__ float waveMax(float v) {
#pragma unroll
    for (int off = 32; off; off >>= 1) v = fmaxf(v, __shfl_xor(v, off, 64));
    return v;
}
__device__ __forceinline__ float waveSum(float v) {
#pragma unroll
    for (int off = 32; off; off >>= 1) v += __shfl_xor(v, off, 64);
    return v;
}
__device__ __forceinline__ int waveSumI(int v) {
#pragma unroll
    for (int off = 32; off; off >>= 1) v += __shfl_xor(v, off, 64);
    return v;
}

// Single-wave block: no s_barrier needed anywhere. DS ops of one wave are
// pipe-ordered; this fence retires all outstanding LDS ops (lgkmcnt==0)
// before later ds_reads issue, and the "memory" clobber stops the compiler
// from reordering LDS accesses across it. Global (vmcnt) loads stay in
// flight across it — emission prefetch rides through.
__device__ __forceinline__ void lds_fence() {
    asm volatile("s_waitcnt lgkmcnt(0)" ::: "memory");
}

// 8 i's (two broadcast float4 e-reads) x 2 output columns packed in f32x2.
// WAv[2j],WAv[2j+1] = W[base+j][k0], W[base+j][k1] (adjacent VGPRs, even-
// aligned inside the f32x16 -> clean v_pk_fma_f32 operands).
#define GRP2(WAv, q, ev, a0, a1, a2, a3) { \
    const float4 ea = ev[2*(q)]; \
    const float4 eb = ev[2*(q)+1]; \
    a0 = __builtin_elementwise_fma((f32x2){ea.x, ea.x}, (f32x2){WAv[0],  WAv[1]},  a0); \
    a1 = __builtin_elementwise_fma((f32x2){ea.y, ea.y}, (f32x2){WAv[2],  WAv[3]},  a1); \
    a2 = __builtin_elementwise_fma((f32x2){ea.z, ea.z}, (f32x2){WAv[4],  WAv[5]},  a2); \
    a3 = __builtin_elementwise_fma((f32x2){ea.w, ea.w}, (f32x2){WAv[6],  WAv[7]},  a3); \
    a0 = __builtin_elementwise_fma((f32x2){eb.x, eb.x}, (f32x2){WAv[8],  WAv[9]},  a0); \
    a1 = __builtin_elementwise_fma((f32x2){eb.y, eb.y}, (f32x2){WAv[10], WAv[11]}, a1); \
    a2 = __builtin_elementwise_fma((f32x2){eb.z, eb.z}, (f32x2){WAv[12], WAv[13]}, a2); \
    a3 = __builtin_elementwise_fma((f32x2){eb.w, eb.w}, (f32x2){WAv[14], WAv[15]}, a3); }

#define LOADW(WAv, base) { \
    _Pragma("unroll") \
    for (int j = 0; j < 8; ++j) { \
        const int i = (base) + j; \
        WAv[2*j]   = forb[i*KK + k0] ? 0.0f : __expf(trans[i*KK + k0]); \
        WAv[2*j+1] = forb[i*KK + k1] ? 0.0f : __expf(trans[i*KK + k1]); \
    } }

struct Bi { float s0, s1, u0, u1; };

// One 64-thread (single-wave) block per batch b. Lane l owns states k0=l,
// k1=l+64 for BOTH chains (sup + unsup), which share the register-resident
// W (16 f32x16 = 256 VGPRs; chain-invariant). waves_per_eu(1,1) gives the
// full 512-VGPR budget: ~200 spare regs let the compiler keep many
// ds_read_b128 in flight — round 6's wall was W=128 + 4 spare regs forcing
// one-at-a-time LDS reads (32 x ~65 cyc ~= the observed 2200 cyc/step).
extern "C" __global__ __launch_bounds__(64)
__attribute__((amdgpu_waves_per_eu(1, 1)))
void crf_pair_kernel(const float* __restrict__ em,
                     const int* __restrict__ mask,
                     const int* __restrict__ tgt,
                     const float* __restrict__ trans,
                     const float* __restrict__ start,
                     const int* __restrict__ forb,
                     float* __restrict__ out)
{
    const int l  = threadIdx.x;          // lane 0..63
    const int k0 = l, k1 = l + 64;
    const int b  = blockIdx.x;

    __shared__ __align__(16) float eS[2][KK];   // sup chain scaled alpha
    __shared__ __align__(16) float eU[2][KK];   // unsup chain scaled alpha

    // ---- length: shuffle-only (single wave) ----
    const int4* __restrict__ mrow4 = (const int4*)(mask + (size_t)b * TT);
    int ps = 0;
#pragma unroll
    for (int q = 0; q < 8; ++q) {
        const int4 m = mrow4[8 * l + q];
        ps += m.x + m.y + m.z + m.w;
    }
    const int len = waveSumI(ps);        // uniform, in [1024, 2048]

    const float st0 = start[k0], st1 = start[k1];
    const float* __restrict__ emrow = em + (size_t)b * TT * KK;
    const int* __restrict__ trow = tgt + (size_t)b * TT * KK;

    // ---- W: 16 f32x16, element 2j/2j+1 = columns k0/k1 of row base+j ----
    f32x16 WA0, WA1, WA2, WA3, WA4, WA5, WA6, WA7,
           WA8, WA9, WA10, WA11, WA12, WA13, WA14, WA15;
    LOADW(WA0, 0)   LOADW(WA1, 8)   LOADW(WA2, 16)  LOADW(WA3, 24)
    LOADW(WA4, 32)  LOADW(WA5, 40)  LOADW(WA6, 48)  LOADW(WA7, 56)
    LOADW(WA8, 64)  LOADW(WA9, 72)  LOADW(WA10, 80) LOADW(WA11, 88)
    LOADW(WA12, 96) LOADW(WA13, 104) LOADW(WA14, 112) LOADW(WA15, 120)

    // ---- t = 0: exact max rescale per chain (shuffle-only) ----
    const float e00 = emrow[k0], e01 = emrow[k1];
    const int   t00 = trow[k0],  t01 = trow[k1];
    const float v0U0 = e00 + st0, v0U1 = e01 + st1;
    const float v0S0 = (t00 ? e00 : -100000.0f) + st0;
    const float v0S1 = (t01 ? e01 : -100000.0f) + st1;
    const float MS0 = waveMax(fmaxf(v0S0, v0S1));
    const float MU0 = waveMax(fmaxf(v0U0, v0U1));
    double MS = (double)MS0, MU = (double)MU0;
    float eNS0 = __expf(v0S0 - MS0), eNS1 = __expf(v0S1 - MS0);
    float eNU0 = __expf(v0U0 - MU0), eNU1 = __expf(v0U1 - MU0);
    eS[0][k0] = eNS0; eS[0][k1] = eNS1;
    eU[0][k0] = eNU0; eU[0][k1] = eNU1;

    auto ld = [&](int t) -> Bi {
        const float a0 = emrow[(size_t)t * KK + k0];
        const float a1 = emrow[(size_t)t * KK + k1];
        const int   m0 = trow[(size_t)t * KK + k0];
        const int   m1 = trow[(size_t)t * KK + k1];
        Bi r;
        r.u0 = a0 + st0; r.u1 = a1 + st1;
        r.s0 = m0 ? r.u0 : (-100000.0f + st0);
        r.s1 = m1 ? r.u1 : (-100000.0f + st1);
        return r;
    };

    Bi biA = {}, biB = {}, biC = {}, biD = {};
    if (len > 1) biA = ld(1);
    if (len > 2) biB = ld(2);
    if (len > 3) biC = ld(3);
    if (len > 4) biD = ld(4);

    // block-renorm state (proven in round 6: measure t%4==3, apply t%4==0)
    float sPS0 = 1.f, sPS1 = 1.f, sPU0 = 1.f, sPU1 = 1.f;
    float bPS0 = 0.f, bPS1 = 0.f, bPU0 = 0.f, bPU1 = 0.f;
    float rSn = 0.f, rUn = 0.f;          // pending shifts (wave-uniform)

    lds_fence();                         // e[0] writes retired

#pragma unroll 4
    for (int t = 1; t < len; ++t) {
        const int p = (t - 1) & 1;
        const Bi biN = (t + 4 < len) ? ld(t + 4) : Bi{};

        // measurement (1 of 4 iters): max_k log e_{t-1}, shuffle-only
        if ((t & 3) == 3) {
            const float uS = fmaxf(__logf(sPS0) + bPS0, __logf(sPS1) + bPS1);
            const float uU = fmaxf(__logf(sPU0) + bPU0, __logf(sPU1) + bPU1);
            rSn = waveMax(uS);
            rUn = waveMax(uU);
        }
        float rS = 0.f, rU = 0.f;
        if ((t & 3) == 0) {              // application (open-loop, stable)
            rS = rSn; rU = rUn;
            MS += (double)rS; MU += (double)rU;
        }
        const float baS0 = biA.s0 - rS, baS1 = biA.s1 - rS;
        const float baU0 = biA.u0 - rU, baU1 = biA.u1 - rU;
        const float fS0 = __expf(baS0), fS1 = __expf(baS1);
        const float fU0 = __expf(baU0), fU1 = __expf(baU1);

        // both chains' matvecs interleaved (independent -> latency hiding)
        const float4* __restrict__ evS = (const float4*)eS[p];
        const float4* __restrict__ evU = (const float4*)eU[p];
        f32x2 aS0 = {0.f,0.f}, aS1 = {0.f,0.f}, aS2 = {0.f,0.f}, aS3 = {0.f,0.f};
        f32x2 aU0 = {0.f,0.f}, aU1 = {0.f,0.f}, aU2 = {0.f,0.f}, aU3 = {0.f,0.f};
        GRP2(WA0, 0, evS, aS0, aS1, aS2, aS3)  GRP2(WA0, 0, evU, aU0, aU1, aU2, aU3)
        GRP2(WA1, 1, evS, aS0, aS1, aS2, aS3)  GRP2(WA1, 1, evU, aU0, aU1, aU2, aU3)
        GRP2(WA2, 2, evS, aS0, aS1, aS2, aS3)  GRP2(WA2, 2, evU, aU0, aU1, aU2, aU3)
        GRP2(WA3, 3, evS, aS0, aS1, aS2, aS3)  GRP2(WA3, 3, evU, aU0, aU1, aU2, aU3)
        GRP2(WA4, 4, evS, aS0, aS1, aS2, aS3)  GRP2(WA4, 4, evU, aU0, aU1, aU2, aU3)
        GRP2(WA5, 5, evS, aS0, aS1, aS2, aS3)  GRP2(WA5, 5, evU, aU0, aU1, aU2, aU3)
        GRP2(WA6, 6, evS, aS0, aS1, aS2, aS3)  GRP2(WA6, 6, evU, aU0, aU1, aU2, aU3)
        GRP2(WA7, 7, evS, aS0, aS1, aS2, aS3)  GRP2(WA7, 7, evU, aU0, aU1, aU2, aU3)
        GRP2(WA8, 8, evS, aS0, aS1, aS2, aS3)  GRP2(WA8, 8, evU, aU0, aU1, aU2, aU3)
        GRP2(WA9, 9, evS, aS0, aS1, aS2, aS3)  GRP2(WA9, 9, evU, aU0, aU1, aU2, aU3)
        GRP2(WA10,10, evS, aS0, aS1, aS2, aS3) GRP2(WA10,10, evU, aU0, aU1, aU2, aU3)
        GRP2(WA11,11, evS, aS0, aS1, aS2, aS3) GRP2(WA11,11, evU, aU0, aU1, aU2, aU3)
        GRP2(WA12,12, evS, aS0, aS1, aS2, aS3) GRP2(WA12,12, evU, aU0, aU1, aU2, aU3)
        GRP2(WA13,13, evS, aS0, aS1, aS2, aS3) GRP2(WA13,13, evU, aU0, aU1, aU2, aU3)
        GRP2(WA14,14, evS, aS0, aS1, aS2, aS3) GRP2(WA14,14, evU, aU0, aU1, aU2, aU3)
        GRP2(WA15,15, evS, aS0, aS1, aS2, aS3) GRP2(WA15,15, evU, aU0, aU1, aU2, aU3)

        const f32x2 sS2 = (aS0 + aS1) + (aS2 + aS3);   // {s_k0, s_k1}
        const f32x2 sU2 = (aU0 + aU1) + (aU2 + aU3);

        // e' = s * exp(bi - r); write early, glue after (off critical path)
        eNS0 = sS2[0] * fS0; eNS1 = sS2[1] * fS1;
        eNU0 = sU2[0] * fU0; eNU1 = sU2[1] * fU1;
        eS[p ^ 1][k0] = eNS0; eS[p ^ 1][k1] = eNS1;
        eU[p ^ 1][k0] = eNU0; eU[p ^ 1][k1] = eNU1;

        sPS0 = sS2[0]; sPS1 = sS2[1]; sPU0 = sU2[0]; sPU1 = sU2[1];
        bPS0 = baS0; bPS1 = baS1; bPU0 = baU0; bPU1 = baU1;
        biA = biB; biB = biC; biC = biD; biD = biN;
        lds_fence();                     // writes retired before next reads
    }

    // ---- z per chain, shuffle-only; out[b] = z_sup - z_unsup ----
    const float smS = waveSum(eNS0 + eNS1);
    const float smU = waveSum(eNU0 + eNU1);
    const double zS = MS + (double)__logf(smS);
    const double zU = MU + (double)__logf(smU);
    if (l == 0) out[b] = (float)(zS - zU);
}

extern "C" void kernel_launch(void* const* d_in, const int* in_sizes, int n_in,
                              void* d_out, int out_size, void* d_ws, size_t ws_size,
                              hipStream_t stream) {
    const float* em    = (const float*)d_in[0];
    const int*   mask  = (const int*)d_in[1];
    const int*   tgt   = (const int*)d_in[2];
    const float* trans = (const float*)d_in[3];
    const float* start = (const float*)d_in[4];
    const int*   forb  = (const int*)d_in[5];

    crf_pair_kernel<<<BB, 64, 0, stream>>>(em, mask, tgt, trans, start, forb,
                                           (float*)d_out);
}

// Round 8
// 1986.410 us; speedup vs baseline: 3.0772x; 3.0772x over previous
//
#include <hip/hip_runtime.h>
#include <stdint.h>

#define BB 64
#define TT 2048
#define KK 128

typedef float f32x16 __attribute__((ext_vector_type(16)));
typedef float f32x2  __attribute__((ext_vector_type(2)));

__device__ __forceinline__ float waveMax(float v) {
#pragma unroll
    for (int off = 32; off; off >>= 1) v = fmaxf(v, __shfl_xor(v, off, 64));
    return v;
}
__device__ __forceinline__ float waveSum(float v) {
#pragma unroll
    for (int off = 32; off; off >>= 1) v += __shfl_xor(v, off, 64);
    return v;
}
__device__ __forceinline__ int waveSumI(int v) {
#pragma unroll
    for (int off = 32; off; off >>= 1) v += __shfl_xor(v, off, 64);
    return v;
}

// lgkm-only barrier: LDS visibility without draining global prefetch (vmcnt).
__device__ __forceinline__ void lds_barrier() {
    asm volatile("s_waitcnt lgkmcnt(0)\n\ts_barrier" ::: "memory");
}

#define PKFMA(ep, wp, acc) acc = __builtin_elementwise_fma(ep, wp, acc)

// One block (512 threads, 8 waves) per chain c: c<64 supervised, else unsup.
// Thread (k = tid>>2, q = tid&3): output state k, i-quarter q (32 i's).
// Per thread per step: 8 ds_read_b128 (hoisted, independent dests), 16
// v_pk_fma_f32, quad-combine via 2 shfl_xor (q-lanes adjacent in wave -> no
// LDS round-trip), 1 lgkm-only barrier. Register demand ~105/thread — small
// enough that the scheduler can hoist all 8 e-reads before first use (the
// round 2..7 wall was serialized read->use ds_read chains at ~65-120 cyc
// each, caused by register-pressure-minimizing scheduling around big W
// hoards; VGPR_Count 56/132/172 across rounds proves the hoards never fully
// materialized anyway).
extern "C" __global__ __launch_bounds__(512)
__attribute__((amdgpu_waves_per_eu(2, 2)))
void crf_chain_kernel(const float* __restrict__ em,
                      const int* __restrict__ mask,
                      const int* __restrict__ tgt,
                      const float* __restrict__ trans,
                      const float* __restrict__ start,
                      const int* __restrict__ forb,
                      float* __restrict__ zbuf)
{
    const int tid  = threadIdx.x;
    const int k    = tid >> 2;          // state 0..127
    const int q    = tid & 3;           // i-quarter
    const int w    = tid >> 6;          // wave 0..7
    const int lane = tid & 63;
    const int c    = blockIdx.x;
    const int b    = c & (BB - 1);
    const bool sup = (c < BB);

    __shared__ __align__(16) float eLDS[2][KK];  // double-buffered scaled alpha
    __shared__ float wmLDS[8];                   // delayed per-wave max(log e)
    __shared__ float redLDS[8];
    __shared__ int lenLDS;

    // ---- length = sum of int32 mask row (4 ints/thread) ----
    if (tid == 0) lenLDS = 0;
    const int4 m4 = ((const int4*)(mask + (size_t)b * TT))[tid];
    int ps = m4.x + m4.y + m4.z + m4.w;
    ps = waveSumI(ps);
    __syncthreads();
    if (lane == 0) atomicAdd(&lenLDS, ps);

    const float st = start[k];
    const float* __restrict__ emrow = em + (size_t)b * TT * KK;
    const int* __restrict__ trow = tgt + (size_t)b * TT * KK;

    // ---- W quarter-column: W[q*32+j][k], j=0..31, in 2 f32x16 (32 VGPRs) ----
    const int ib = q * 32;
    f32x16 Wa, Wb;
#pragma unroll
    for (int j = 0; j < 16; ++j) {
        Wa[j] = forb[(ib + j     ) * KK + k] ? 0.0f : __expf(trans[(ib + j     ) * KK + k]);
        Wb[j] = forb[(ib + 16 + j) * KK + k] ? 0.0f : __expf(trans[(ib + 16 + j) * KK + k]);
    }

    // ---- t = 0: exact max rescale (one-time) ----
    float v0 = emrow[k];
    if (sup && !trow[k]) v0 = -100000.0f;
    v0 += st;
    const float wm0 = waveMax(v0);
    if (lane == 0) redLDS[w] = wm0;
    __syncthreads();
    const int len = lenLDS;                      // uniform, in [1024, 2048]
    float M0 = fmaxf(redLDS[0], redLDS[1]);
    M0 = fmaxf(M0, fmaxf(redLDS[2], redLDS[3]));
    M0 = fmaxf(M0, fmaxf(redLDS[4], redLDS[5]));
    M0 = fmaxf(M0, fmaxf(redLDS[6], redLDS[7]));
    double M = (double)M0;                       // running log-scale, fp64
    float eNew = __expf(v0 - M0);
    if (q == 0) eLDS[0][k] = eNew;

    auto bival = [&](int t) -> float {
        float e0 = emrow[(size_t)t * KK + k];    // quad lanes share addr: broadcast
        if (sup) { if (!trow[(size_t)t * KK + k]) e0 = -100000.0f; }
        return e0 + st;
    };

    // bi pipeline, depth 4 (rides across lgkm-only barriers)
    float biA = (len > 1) ? bival(1) : 0.0f;
    float biB = (len > 2) ? bival(2) : 0.0f;
    float biC = (len > 3) ? bival(3) : 0.0f;
    float biD = (len > 4) ? bival(4) : 0.0f;

    float sPrev = 1.0f, baPrev = 0.0f;
    lds_barrier();                               // publish eLDS[0]

#pragma unroll 4
    for (int t = 1; t < len; ++t) {
        const int p = (t - 1) & 1;
        const float biN = (t + 4 < len) ? bival(t + 4) : 0.0f;

        // measurement (1 of 4 iters): max_k log e_{t-1} (dup x4 over q: same s)
        if ((t & 3) == 3) {
            const float u = __logf(sPrev) + baPrev;  // -inf for dead states: ok
            const float wmx = waveMax(u);
            if (lane == 0) wmLDS[w] = wmx;
        }
        // application (1 of 4 iters): open-loop block renorm (proven R6)
        float r = 0.0f;
        if ((t & 3) == 0) {
            float rr = fmaxf(wmLDS[0], wmLDS[1]);
            rr = fmaxf(rr, fmaxf(wmLDS[2], wmLDS[3]));
            rr = fmaxf(rr, fmaxf(wmLDS[4], wmLDS[5]));
            rr = fmaxf(rr, fmaxf(wmLDS[6], wmLDS[7]));
            r = rr;
            M += (double)r;
        }
        const float ba = biA - r;
        const float f = __expf(ba);              // off critical path (early)

        // phase 1: ALL 8 e-chunk reads, independent destinations (hoistable)
        const float4* __restrict__ ev = (const float4*)eLDS[p] + q * 8;
        const float4 e0 = ev[0], e1 = ev[1], e2 = ev[2], e3 = ev[3];
        const float4 e4 = ev[4], e5 = ev[5], e6 = ev[6], e7 = ev[7];

        // phase 2: 16 v_pk_fma_f32 over the quarter
        f32x2 a0 = {0.f,0.f}, a1 = {0.f,0.f}, a2 = {0.f,0.f}, a3 = {0.f,0.f};
        PKFMA(((f32x2){e0.x, e0.y}), ((f32x2){Wa[0],  Wa[1]}),  a0);
        PKFMA(((f32x2){e0.z, e0.w}), ((f32x2){Wa[2],  Wa[3]}),  a1);
        PKFMA(((f32x2){e1.x, e1.y}), ((f32x2){Wa[4],  Wa[5]}),  a2);
        PKFMA(((f32x2){e1.z, e1.w}), ((f32x2){Wa[6],  Wa[7]}),  a3);
        PKFMA(((f32x2){e2.x, e2.y}), ((f32x2){Wa[8],  Wa[9]}),  a0);
        PKFMA(((f32x2){e2.z, e2.w}), ((f32x2){Wa[10], Wa[11]}), a1);
        PKFMA(((f32x2){e3.x, e3.y}), ((f32x2){Wa[12], Wa[13]}), a2);
        PKFMA(((f32x2){e3.z, e3.w}), ((f32x2){Wa[14], Wa[15]}), a3);
        PKFMA(((f32x2){e4.x, e4.y}), ((f32x2){Wb[0],  Wb[1]}),  a0);
        PKFMA(((f32x2){e4.z, e4.w}), ((f32x2){Wb[2],  Wb[3]}),  a1);
        PKFMA(((f32x2){e5.x, e5.y}), ((f32x2){Wb[4],  Wb[5]}),  a2);
        PKFMA(((f32x2){e5.z, e5.w}), ((f32x2){Wb[6],  Wb[7]}),  a3);
        PKFMA(((f32x2){e6.x, e6.y}), ((f32x2){Wb[8],  Wb[9]}),  a0);
        PKFMA(((f32x2){e6.z, e6.w}), ((f32x2){Wb[10], Wb[11]}), a1);
        PKFMA(((f32x2){e7.x, e7.y}), ((f32x2){Wb[12], Wb[13]}), a2);
        PKFMA(((f32x2){e7.z, e7.w}), ((f32x2){Wb[14], Wb[15]}), a3);
        const f32x2 s2 = (a0 + a1) + (a2 + a3);
        float s = s2[0] + s2[1];
        // quad combine: q-lanes adjacent in wave -> 2 shfl_xor, no LDS
        s += __shfl_xor(s, 1, 64);
        s += __shfl_xor(s, 2, 64);

        eNew = s * f;                            // the only on-path math
        if (q == 0) eLDS[p ^ 1][k] = eNew;       // 16 lanes/wave, distinct banks

        sPrev = s; baPrev = ba;
        biA = biB; biB = biC; biC = biD; biD = biN;
        lds_barrier();                           // single barrier/step
    }

    // ---- z = M + log(sum_k e_{len-1}) ----
    const float sm = waveSum((q == 0) ? eNew : 0.0f);
    if (lane == 0) redLDS[w] = sm;
    __syncthreads();
    if (tid == 0) {
        const float ss = ((redLDS[0] + redLDS[1]) + (redLDS[2] + redLDS[3]))
                       + ((redLDS[4] + redLDS[5]) + (redLDS[6] + redLDS[7]));
        zbuf[c] = (float)(M + (double)__logf(ss));
    }
}

extern "C" __global__ void crf_final_kernel(const float* __restrict__ z,
                                            float* __restrict__ out)
{
    const int b = threadIdx.x;
    out[b] = z[b] - z[b + BB];
}

extern "C" void kernel_launch(void* const* d_in, const int* in_sizes, int n_in,
                              void* d_out, int out_size, void* d_ws, size_t ws_size,
                              hipStream_t stream) {
    const float* em    = (const float*)d_in[0];
    const int*   mask  = (const int*)d_in[1];
    const int*   tgt   = (const int*)d_in[2];
    const float* trans = (const float*)d_in[3];
    const float* start = (const float*)d_in[4];
    const int*   forb  = (const int*)d_in[5];
    float* zbuf = (float*)d_ws;   // 128 per-chain log-partition values

    crf_chain_kernel<<<2 * BB, 512, 0, stream>>>(em, mask, tgt, trans, start, forb, zbuf);
    crf_final_kernel<<<1, BB, 0, stream>>>(zbuf, (float*)d_out);
}

// Round 9
// 925.693 us; speedup vs baseline: 6.6033x; 2.1459x over previous
//
#include <hip/hip_runtime.h>
#include <stdint.h>

#define BB 64
#define TT 2048
#define KK 128
#define QSTRIDE 40   // words per e-quarter: banks {0,8,16,24}+4j -> conflict-free

typedef float f32x16 __attribute__((ext_vector_type(16)));
typedef float f32x2  __attribute__((ext_vector_type(2)));

__device__ __forceinline__ float waveMax(float v) {
#pragma unroll
    for (int off = 32; off; off >>= 1) v = fmaxf(v, __shfl_xor(v, off, 64));
    return v;
}
__device__ __forceinline__ float waveSum(float v) {
#pragma unroll
    for (int off = 32; off; off >>= 1) v += __shfl_xor(v, off, 64);
    return v;
}
__device__ __forceinline__ int waveSumI(int v) {
#pragma unroll
    for (int off = 32; off; off >>= 1) v += __shfl_xor(v, off, 64);
    return v;
}
// quad reduction via DPP quad_perm (VALU-speed; replaces 2 ds_bpermute)
__device__ __forceinline__ float quadSum(float s) {
    int x = __builtin_amdgcn_mov_dpp(__float_as_int(s), 0xB1, 0xf, 0xf, true); // xor1
    s += __int_as_float(x);
    x = __builtin_amdgcn_mov_dpp(__float_as_int(s), 0x4E, 0xf, 0xf, true);     // xor2
    s += __int_as_float(x);
    return s;
}
__device__ __forceinline__ float waveMaxFast(float v) {
    int x = __builtin_amdgcn_mov_dpp(__float_as_int(v), 0xB1, 0xf, 0xf, true);
    v = fmaxf(v, __int_as_float(x));
    x = __builtin_amdgcn_mov_dpp(__float_as_int(v), 0x4E, 0xf, 0xf, true);
    v = fmaxf(v, __int_as_float(x));
#pragma unroll
    for (int off = 4; off <= 32; off <<= 1) v = fmaxf(v, __shfl_xor(v, off, 64));
    return v;
}

// lgkm-only barrier: LDS visibility without draining global prefetch (vmcnt).
__device__ __forceinline__ void lds_barrier() {
    asm volatile("s_waitcnt lgkmcnt(0)\n\ts_barrier" ::: "memory");
}

#define PKFMA(ep, wp, acc) acc = __builtin_elementwise_fma(ep, wp, acc)

#define MATVEC_QUARTER(Wa, Wb, ev, sOut) {                          \
    const float4 e0 = ev[0], e1 = ev[1], e2 = ev[2], e3 = ev[3];    \
    const float4 e4 = ev[4], e5 = ev[5], e6 = ev[6], e7 = ev[7];    \
    f32x2 a0 = {0.f,0.f}, a1 = {0.f,0.f}, a2 = {0.f,0.f}, a3 = {0.f,0.f}; \
    PKFMA(((f32x2){e0.x, e0.y}), ((f32x2){Wa[0],  Wa[1]}),  a0);    \
    PKFMA(((f32x2){e0.z, e0.w}), ((f32x2){Wa[2],  Wa[3]}),  a1);    \
    PKFMA(((f32x2){e1.x, e1.y}), ((f32x2){Wa[4],  Wa[5]}),  a2);    \
    PKFMA(((f32x2){e1.z, e1.w}), ((f32x2){Wa[6],  Wa[7]}),  a3);    \
    PKFMA(((f32x2){e2.x, e2.y}), ((f32x2){Wa[8],  Wa[9]}),  a0);    \
    PKFMA(((f32x2){e2.z, e2.w}), ((f32x2){Wa[10], Wa[11]}), a1);    \
    PKFMA(((f32x2){e3.x, e3.y}), ((f32x2){Wa[12], Wa[13]}), a2);    \
    PKFMA(((f32x2){e3.z, e3.w}), ((f32x2){Wa[14], Wa[15]}), a3);    \
    PKFMA(((f32x2){e4.x, e4.y}), ((f32x2){Wb[0],  Wb[1]}),  a0);    \
    PKFMA(((f32x2){e4.z, e4.w}), ((f32x2){Wb[2],  Wb[3]}),  a1);    \
    PKFMA(((f32x2){e5.x, e5.y}), ((f32x2){Wb[4],  Wb[5]}),  a2);    \
    PKFMA(((f32x2){e5.z, e5.w}), ((f32x2){Wb[6],  Wb[7]}),  a3);    \
    PKFMA(((f32x2){e6.x, e6.y}), ((f32x2){Wb[8],  Wb[9]}),  a0);    \
    PKFMA(((f32x2){e6.z, e6.w}), ((f32x2){Wb[10], Wb[11]}), a1);    \
    PKFMA(((f32x2){e7.x, e7.y}), ((f32x2){Wb[12], Wb[13]}), a2);    \
    PKFMA(((f32x2){e7.z, e7.w}), ((f32x2){Wb[14], Wb[15]}), a3);    \
    const f32x2 s2 = (a0 + a1) + (a2 + a3);                         \
    sOut = s2[0] + s2[1]; }

// Forward/backward meet-in-the-middle. Grid 256: block i<128 runs the FORWARD
// recursion of chain i (alpha), block 128+i runs the BACKWARD recursion
// (beta: d_{t-1} = W . (d_t o exp(bi_t - r)) -- identical dataflow, W
// row-gathered instead of column-gathered). Each runs ~len/2 serial steps
// instead of len: the per-step cost (~2250 cyc) was shown structural across
// R4/R6/R8 (DS-read count per chain-step invariant), so halving steps is the
// lever. Meet: z = Mf + Mb + log(sum_k ef[k]*db[k]) in a combine kernel.
extern "C" __global__ __launch_bounds__(512)
void crf_fb_kernel(const float* __restrict__ em,
                   const int* __restrict__ mask,
                   const int* __restrict__ tgt,
                   const float* __restrict__ trans,
                   const float* __restrict__ start,
                   const int* __restrict__ forb,
                   float* __restrict__ ef,      // [128][KK] forward exp-alpha
                   float* __restrict__ db,      // [128][KK] backward exp-beta
                   float* __restrict__ Mfb)     // [256] scales: fwd 0..127, bwd 128..255
{
    const int tid  = threadIdx.x;
    const int k    = tid >> 2;          // out-state (fwd) / out-row (bwd)
    const int q    = tid & 3;           // inner quarter
    const int w    = tid >> 6;
    const int lane = tid & 63;
    const bool fwdDir = (blockIdx.x < 2 * BB);
    const int c    = blockIdx.x & (2 * BB - 1);
    const int b    = c & (BB - 1);
    const bool sup = (c < BB);

    __shared__ __align__(16) float eLDS[2][3 * QSTRIDE + 32]; // swizzled e
    __shared__ float wmLDS[8];
    __shared__ float redLDS[8];
    __shared__ int lenLDS;

    // ---- length ----
    if (tid == 0) lenLDS = 0;
    const int4 m4 = ((const int4*)(mask + (size_t)b * TT))[tid];
    int ps = m4.x + m4.y + m4.z + m4.w;
    ps = waveSumI(ps);
    __syncthreads();
    if (lane == 0) atomicAdd(&lenLDS, ps);

    const float st = start[k];
    const float* __restrict__ emrow = em + (size_t)b * TT * KK;
    const int* __restrict__ trow = tgt + (size_t)b * TT * KK;

    // ---- W quarter (fwd: column k of W; bwd: row k of W) ----
    const int ib = q * 32;
    f32x16 Wa, Wb;
    if (fwdDir) {
#pragma unroll
        for (int j = 0; j < 16; ++j) {
            Wa[j] = forb[(ib + j     ) * KK + k] ? 0.0f : __expf(trans[(ib + j     ) * KK + k]);
            Wb[j] = forb[(ib + 16 + j) * KK + k] ? 0.0f : __expf(trans[(ib + 16 + j) * KK + k]);
        }
    } else {
#pragma unroll
        for (int j = 0; j < 16; ++j) {
            Wa[j] = forb[k * KK + ib + j     ] ? 0.0f : __expf(trans[k * KK + ib + j     ]);
            Wb[j] = forb[k * KK + ib + 16 + j] ? 0.0f : __expf(trans[k * KK + ib + 16 + j]);
        }
    }
    __syncthreads();                     // lenLDS ready
    const int len = lenLDS;              // uniform, in [1024, 2048]
    const int mid = len >> 1;
    const int N   = fwdDir ? mid : (len - 1 - mid);   // serial steps (>=511)
    const int t0  = fwdDir ? 0 : (len - 1);

    // ---- init vector at t0: exact max renorm ----
    float v0 = emrow[(size_t)t0 * KK + k];
    if (sup && !trow[(size_t)t0 * KK + k]) v0 = -100000.0f;
    v0 += st;
    const float wm0 = waveMax(v0);
    if (lane == 0) redLDS[w] = wm0;
    __syncthreads();
    float M0 = fmaxf(fmaxf(fmaxf(redLDS[0], redLDS[1]), fmaxf(redLDS[2], redLDS[3])),
                     fmaxf(fmaxf(redLDS[4], redLDS[5]), fmaxf(redLDS[6], redLDS[7])));
    double M = (double)M0;
    float eNew = __expf(v0 - M0);
    if (q == 0) eLDS[0][(k >> 5) * QSTRIDE + (k & 31)] = eNew;

    auto bival = [&](int t) -> float {
        float e0 = emrow[(size_t)t * KK + k];
        if (sup) { if (!trow[(size_t)t * KK + k]) e0 = -100000.0f; }
        return e0 + st;
    };
    // iter n consumes bi[time]: fwd time=n; bwd time=len-1-n except the final
    // bwd iter which must NOT apply bi_mid (forward already owns it) -> bi:=0.
    auto loadBi = [&](int n) -> float {
        if (n > N || (!fwdDir && n == N)) return 0.0f;
        const int t = fwdDir ? n : (len - 1 - n);
        return bival(t);
    };

    float biA = loadBi(1), biB = loadBi(2), biC = loadBi(3), biD = loadBi(4);
    float sPrev = 1.0f, baPrev = 0.0f;
    lds_barrier();                       // publish eLDS[0]

#pragma unroll 4
    for (int n = 1; n <= N; ++n) {
        const int p = (n - 1) & 1;
        const float biN = loadBi(n + 4); // rides across lgkm-only barriers

        // block-renorm (proven R6): measure at n%4==3, apply at n%4==0
        if ((n & 3) == 3) {
            const float u = __logf(sPrev) + baPrev;  // -inf for dead states: ok
            const float wmx = waveMaxFast(u);
            if (lane == 0) wmLDS[w] = wmx;
        }
        float r = 0.0f;
        if ((n & 3) == 0) {
            r = fmaxf(fmaxf(fmaxf(wmLDS[0], wmLDS[1]), fmaxf(wmLDS[2], wmLDS[3])),
                      fmaxf(fmaxf(wmLDS[4], wmLDS[5]), fmaxf(wmLDS[6], wmLDS[7])));
            M += (double)r;
        }
        const float ba = biA - r;
        const float f = __expf(ba);      // off critical path (early)

        const float4* __restrict__ ev = (const float4*)(&eLDS[p][q * QSTRIDE]);
        float s;
        MATVEC_QUARTER(Wa, Wb, ev, s)
        s = quadSum(s);                  // DPP, no DS pipe

        eNew = s * f;
        if (q == 0) eLDS[p ^ 1][(k >> 5) * QSTRIDE + (k & 31)] = eNew;

        sPrev = s; baPrev = ba;
        biA = biB; biB = biC; biC = biD; biD = biN;
        lds_barrier();                   // single barrier/step, lgkm-only
    }

    if (q == 0) { (fwdDir ? ef : db)[(size_t)c * KK + k] = eNew; }
    if (tid == 0) Mfb[(fwdDir ? 0 : 2 * BB) + c] = (float)M;
}

// z[c] = Mf[c] + Mb[c] + log(dot(ef[c], db[c])); out[b] = z[b] - z[b+64]
extern "C" __global__ void crf_combine_kernel(const float* __restrict__ ef,
                                              const float* __restrict__ db,
                                              const float* __restrict__ Mfb,
                                              float* __restrict__ out)
{
    const int b = blockIdx.x;
    const int tid = threadIdx.x;         // 0..127 = state
    const int wv = tid >> 6, lane = tid & 63;
    __shared__ float red[2][2];
    __shared__ float z[2];
#pragma unroll
    for (int s = 0; s < 2; ++s) {
        const int c = b + s * BB;
        const float v = ef[(size_t)c * KK + tid] * db[(size_t)c * KK + tid];
        const float p = waveSum(v);
        if (lane == 0) red[s][wv] = p;
    }
    __syncthreads();
    if (tid < 2) {
        const int c = b + tid * BB;
        z[tid] = Mfb[c] + Mfb[2 * BB + c] + __logf(red[tid][0] + red[tid][1]);
    }
    __syncthreads();
    if (tid == 0) out[b] = z[0] - z[1];
}

// ---------------- fallback (R8, proven): used only if ws is too small -------
extern "C" __global__ __launch_bounds__(512)
__attribute__((amdgpu_waves_per_eu(2, 2)))
void crf_chain_kernel(const float* __restrict__ em, const int* __restrict__ mask,
                      const int* __restrict__ tgt, const float* __restrict__ trans,
                      const float* __restrict__ start, const int* __restrict__ forb,
                      float* __restrict__ zbuf)
{
    const int tid = threadIdx.x;
    const int k = tid >> 2, q = tid & 3, w = tid >> 6, lane = tid & 63;
    const int c = blockIdx.x, b = c & (BB - 1);
    const bool sup = (c < BB);
    __shared__ __align__(16) float eLDS[2][KK];
    __shared__ float wmLDS[8];
    __shared__ float redLDS[8];
    __shared__ int lenLDS;
    if (tid == 0) lenLDS = 0;
    const int4 m4 = ((const int4*)(mask + (size_t)b * TT))[tid];
    int ps = m4.x + m4.y + m4.z + m4.w;
    ps = waveSumI(ps);
    __syncthreads();
    if (lane == 0) atomicAdd(&lenLDS, ps);
    const float st = start[k];
    const float* __restrict__ emrow = em + (size_t)b * TT * KK;
    const int* __restrict__ trow = tgt + (size_t)b * TT * KK;
    const int ib = q * 32;
    f32x16 Wa, Wb;
#pragma unroll
    for (int j = 0; j < 16; ++j) {
        Wa[j] = forb[(ib + j     ) * KK + k] ? 0.0f : __expf(trans[(ib + j     ) * KK + k]);
        Wb[j] = forb[(ib + 16 + j) * KK + k] ? 0.0f : __expf(trans[(ib + 16 + j) * KK + k]);
    }
    float v0 = emrow[k];
    if (sup && !trow[k]) v0 = -100000.0f;
    v0 += st;
    const float wm0 = waveMax(v0);
    if (lane == 0) redLDS[w] = wm0;
    __syncthreads();
    const int len = lenLDS;
    float M0 = fmaxf(fmaxf(fmaxf(redLDS[0], redLDS[1]), fmaxf(redLDS[2], redLDS[3])),
                     fmaxf(fmaxf(redLDS[4], redLDS[5]), fmaxf(redLDS[6], redLDS[7])));
    double M = (double)M0;
    float eNew = __expf(v0 - M0);
    if (q == 0) eLDS[0][k] = eNew;
    auto bival = [&](int t) -> float {
        float e0 = emrow[(size_t)t * KK + k];
        if (sup) { if (!trow[(size_t)t * KK + k]) e0 = -100000.0f; }
        return e0 + st;
    };
    float biA = (len > 1) ? bival(1) : 0.0f;
    float biB = (len > 2) ? bival(2) : 0.0f;
    float biC = (len > 3) ? bival(3) : 0.0f;
    float biD = (len > 4) ? bival(4) : 0.0f;
    float sPrev = 1.0f, baPrev = 0.0f;
    lds_barrier();
#pragma unroll 4
    for (int t = 1; t < len; ++t) {
        const int p = (t - 1) & 1;
        const float biN = (t + 4 < len) ? bival(t + 4) : 0.0f;
        if ((t & 3) == 3) {
            const float u = __logf(sPrev) + baPrev;
            const float wmx = waveMaxFast(u);
            if (lane == 0) wmLDS[w] = wmx;
        }
        float r = 0.0f;
        if ((t & 3) == 0) {
            r = fmaxf(fmaxf(fmaxf(wmLDS[0], wmLDS[1]), fmaxf(wmLDS[2], wmLDS[3])),
                      fmaxf(fmaxf(wmLDS[4], wmLDS[5]), fmaxf(wmLDS[6], wmLDS[7])));
            M += (double)r;
        }
        const float ba = biA - r;
        const float f = __expf(ba);
        const float4* __restrict__ ev = (const float4*)eLDS[p] + q * 8;
        float s;
        MATVEC_QUARTER(Wa, Wb, ev, s)
        s = quadSum(s);
        eNew = s * f;
        if (q == 0) eLDS[p ^ 1][k] = eNew;
        sPrev = s; baPrev = ba;
        biA = biB; biB = biC; biC = biD; biD = biN;
        lds_barrier();
    }
    const float sm = waveSum((q == 0) ? eNew : 0.0f);
    if (lane == 0) redLDS[w] = sm;
    __syncthreads();
    if (tid == 0) {
        const float ss = ((redLDS[0] + redLDS[1]) + (redLDS[2] + redLDS[3]))
                       + ((redLDS[4] + redLDS[5]) + (redLDS[6] + redLDS[7]));
        zbuf[c] = (float)(M + (double)__logf(ss));
    }
}

extern "C" __global__ void crf_final_kernel(const float* __restrict__ z,
                                            float* __restrict__ out)
{
    const int b = threadIdx.x;
    out[b] = z[b] - z[b + BB];
}

extern "C" void kernel_launch(void* const* d_in, const int* in_sizes, int n_in,
                              void* d_out, int out_size, void* d_ws, size_t ws_size,
                              hipStream_t stream) {
    const float* em    = (const float*)d_in[0];
    const int*   mask  = (const int*)d_in[1];
    const int*   tgt   = (const int*)d_in[2];
    const float* trans = (const float*)d_in[3];
    const float* start = (const float*)d_in[4];
    const int*   forb  = (const int*)d_in[5];

    const size_t need = (size_t)(2 * 2 * BB * KK + 4 * BB) * sizeof(float); // 132 KB
    if (ws_size >= need) {
        float* ef  = (float*)d_ws;                       // [128][128]
        float* db  = ef + 2 * BB * KK;                   // [128][128]
        float* Mfb = db + 2 * BB * KK;                   // [256]
        crf_fb_kernel<<<4 * BB, 512, 0, stream>>>(em, mask, tgt, trans, start,
                                                  forb, ef, db, Mfb);
        crf_combine_kernel<<<BB, 128, 0, stream>>>(ef, db, Mfb, (float*)d_out);
    } else {
        float* zbuf = (float*)d_ws;
        crf_chain_kernel<<<2 * BB, 512, 0, stream>>>(em, mask, tgt, trans, start,
                                                     forb, zbuf);
        crf_final_kernel<<<1, BB, 0, stream>>>(zbuf, (float*)d_out);
    }
}